// Round 5
// baseline (791.507 us; speedup 1.0000x reference)
//
#include <hip/hip_runtime.h>

// Problem constants
#define S_  2048
#define D_  1024
#define H_  16
#define B_  4

typedef __attribute__((ext_vector_type(8))) short short8;
typedef __attribute__((ext_vector_type(4))) float f32x4;
typedef __attribute__((ext_vector_type(2))) _Float16 half2v;

__device__ __forceinline__ unsigned short f2bf(float f) {
  unsigned int u = __float_as_uint(f);
  u += 0x7fffu + ((u >> 16) & 1u);      // round-to-nearest-even
  return (unsigned short)(u >> 16);
}
__device__ __forceinline__ unsigned int pack2(float a, float b) {
  return (unsigned int)f2bf(a) | ((unsigned int)f2bf(b) << 16);
}

// 0.125 (1/sqrt(DK)) * log2(e): use exp2 (native v_exp_f32)
#define SCL   0.18033688011112042f
#define EBIAS 12.0f   // uniform bias keeps e' in fp16 range; cancels in softmax

// ---------------------------------------------------------------------------
// x (B,S,D) f32 -> xh (B,H,S,64) bf16 head-major (256 KB contiguous per bh).
// ---------------------------------------------------------------------------
__global__ __launch_bounds__(256) void xcvt(const float* __restrict__ x,
                                            unsigned short* __restrict__ xh) {
  const int n = blockIdx.x;
  const int bh = n >> 5, chunk = n & 31;
  const int b = bh >> 4, h = bh & 15;
  const int r = threadIdx.x >> 2, cg = threadIdx.x & 3;
  const int srow = chunk * 64 + r;
  const float* src = x + ((size_t)b * S_ + srow) * D_ + h * 64 + cg * 16;
  float4 v0 = ((const float4*)src)[0];
  float4 v1 = ((const float4*)src)[1];
  float4 v2 = ((const float4*)src)[2];
  float4 v3 = ((const float4*)src)[3];
  uint4 w0, w1;
  w0.x = pack2(v0.x, v0.y); w0.y = pack2(v0.z, v0.w);
  w0.z = pack2(v1.x, v1.y); w0.w = pack2(v1.z, v1.w);
  w1.x = pack2(v2.x, v2.y); w1.y = pack2(v2.z, v2.w);
  w1.z = pack2(v3.x, v3.y); w1.w = pack2(v3.z, v3.w);
  unsigned short* dst = xh + ((size_t)bh * S_ + srow) * 64 + cg * 16;
  *(uint4*)dst = w0;
  *(uint4*)(dst + 8) = w1;
}

// ---------------------------------------------------------------------------
// Single-pass fused attention.
// Block = 256 thr (4 waves), 32 q-rows, full S. Wave w: rows (w>>1)*16..+16,
// keys (w&1)*1024..+1024. K staged per 2x128-key chunk into XOR-swizzled LDS
// (reg prefetch overlaps compute). e' kept as packed fp16 in 128 VGPRs.
// Epilogue: per-wave LDS transpose -> 128B/row contiguous nt stores; column
// sums via shuffle + LDS, flushed as fixed-point u64 atomics (deterministic).
// grid = 64 bh * 64 qt = 4096, XCD-swizzled (8 bh per XCD, 2 MB L2 set).
// ---------------------------------------------------------------------------
__global__ __launch_bounds__(256, 2) void attn_fused(
    const unsigned short* __restrict__ xh, const int* __restrict__ sl32,
    float* __restrict__ attn, unsigned long long* __restrict__ c64)
{
  __shared__ __align__(16) unsigned short kbuf[256 * 64];  // 32 KB: 2 chunks
  __shared__ __align__(16) float twbuf[4][16 * 36];        // 9216 B transpose
  __shared__ float colacc[2][2048];                        // 16 KB col sums
  __shared__ float wbuf[4][16];
  __shared__ float invbuf[2][16];

  const int n    = blockIdx.x;
  const int xcd  = n & 7;
  const int slot = n >> 3;                 // 0..511 per XCD
  const int bh   = (slot >> 6) * 8 + xcd;  // 8 bh-slices per XCD
  const int qt   = slot & 63;              // 64 q-tiles of 32 rows
  const int b    = bh >> 4;
  const int tid  = threadIdx.x;
  const int wv   = tid >> 6;
  const int lane = tid & 63;
  const int lo   = lane & 15;
  const int g    = lane >> 4;

  // seq_lens dtype auto-detect (values >= 1024 -> int64 layout has word1==0)
  const bool is64 = (sl32[1] == 0);
  const int seqlen = is64 ? sl32[2 * b] : sl32[b];

  const unsigned short* xk = xh + (size_t)bh * S_ * 64;
  const int qrow0 = qt * 32 + (wv >> 1) * 16;

  // Q fragment (A-frag): row = lo, k = g*8 + i (+32)
  short8 aq0 = *(const short8*)(xk + (size_t)(qrow0 + lo) * 64 + g * 8);
  short8 aq1 = *(const short8*)(xk + (size_t)(qrow0 + lo) * 64 + g * 8 + 32);

  // Staging: thread covers 128B of the 32KB 2-chunk region, coalesced 16B.
  const int srow = tid >> 3;     // + i*32 -> LDS row 0..255
  const int su   = tid & 7;      // 16B unit within row (LDS position)

  uint4 streg[8];
  auto prefetch = [&](int c) {
#pragma unroll
    for (int i = 0; i < 8; ++i) {
      const int row = srow + i * 32;
      const int key = c * 128 + (row & 127) + (row >> 7) * 1024;
      const int u   = su ^ (row & 7);            // pre-swizzled source unit
      streg[i] = *(const uint4*)(xk + (size_t)key * 64 + u * 8);
    }
  };
  auto commit = [&]() {
#pragma unroll
    for (int i = 0; i < 8; ++i) {
      const int row = srow + i * 32;
      *(uint4*)&kbuf[row * 64 + su * 8] = streg[i];
    }
  };

  // ---------------- Single QK^T + exp pass, e' -> 128 VGPRs ----------------
  unsigned int ev[128];
  float rsum[4] = {0.f, 0.f, 0.f, 0.f};
  prefetch(0);
#pragma unroll
  for (int c = 0; c < 8; ++c) {
    __syncthreads();                 // previous chunk fully consumed
    commit();
    __syncthreads();                 // staged data visible
    if (c < 7) prefetch(c + 1);      // overlap next loads with compute
    const int kwbase = (wv & 1) * 1024 + c * 128;
#pragma unroll
    for (int kt = 0; kt < 8; ++kt) {
      const int ldsrow = (wv & 1) * 128 + kt * 16 + lo;
      const int cs = g ^ (lo & 7);
      short8 b0 = *(const short8*)&kbuf[ldsrow * 64 + cs * 8];
      short8 b1 = *(const short8*)&kbuf[ldsrow * 64 + (cs ^ 4) * 8];
      f32x4 acc = {0.f, 0.f, 0.f, 0.f};
      acc = __builtin_amdgcn_mfma_f32_16x16x32_bf16(aq0, b0, acc, 0, 0, 0);
      acc = __builtin_amdgcn_mfma_f32_16x16x32_bf16(aq1, b1, acc, 0, 0, 0);
      const bool valid = (kwbase + kt * 16 + lo) < seqlen;
      float e0 = valid ? exp2f(acc[0] * SCL - EBIAS) : 0.f;
      float e1 = valid ? exp2f(acc[1] * SCL - EBIAS) : 0.f;
      float e2 = valid ? exp2f(acc[2] * SCL - EBIAS) : 0.f;
      float e3 = valid ? exp2f(acc[3] * SCL - EBIAS) : 0.f;
      rsum[0] += e0; rsum[1] += e1; rsum[2] += e2; rsum[3] += e3;
      ev[(c * 8 + kt) * 2 + 0] =
          __builtin_bit_cast(unsigned int, __builtin_amdgcn_cvt_pkrtz(e0, e1));
      ev[(c * 8 + kt) * 2 + 1] =
          __builtin_bit_cast(unsigned int, __builtin_amdgcn_cvt_pkrtz(e2, e3));
    }
  }

  // ---------------- Row sums: reduce over lo, combine key halves ----------
#pragma unroll
  for (int r = 0; r < 4; ++r) {
    float v = rsum[r];
    v += __shfl_xor(v, 1);
    v += __shfl_xor(v, 2);
    v += __shfl_xor(v, 4);
    v += __shfl_xor(v, 8);
    if (lo == 0) wbuf[wv][g * 4 + r] = v;
  }
  __syncthreads();
  if (tid < 32) {
    const int p = tid >> 4, i = tid & 15;
    invbuf[p][i] = 1.0f / (wbuf[2 * p][i] + wbuf[2 * p + 1][i]);
  }
  __syncthreads();
  float vinv[4];
#pragma unroll
  for (int r = 0; r < 4; ++r) vinv[r] = invbuf[wv >> 1][g * 4 + r];

  // ---------------- Write phase: transpose -> contiguous stores -----------
  float* abase = attn + (size_t)bh * S_ * S_;
  float* tw = &twbuf[wv][0];
#pragma unroll
  for (int c = 0; c < 8; ++c) {
#pragma unroll
    for (int sub = 0; sub < 4; ++sub) {      // 2 kt tiles = 32 cols each
#pragma unroll
      for (int k2 = 0; k2 < 2; ++k2) {
        const int kt = sub * 2 + k2;
        half2v h0 = __builtin_bit_cast(half2v, ev[(c * 8 + kt) * 2 + 0]);
        half2v h1 = __builtin_bit_cast(half2v, ev[(c * 8 + kt) * 2 + 1]);
        const int colw = k2 * 16 + lo;
        tw[(g * 4 + 0) * 36 + colw] = (float)h0[0] * vinv[0];
        tw[(g * 4 + 1) * 36 + colw] = (float)h0[1] * vinv[1];
        tw[(g * 4 + 2) * 36 + colw] = (float)h1[0] * vinv[2];
        tw[(g * 4 + 3) * 36 + colw] = (float)h1[1] * vinv[3];
      }
      const int gc = (wv & 1) * 1024 + c * 128 + sub * 32;
      f32x4 vcs = {0.f, 0.f, 0.f, 0.f};
#pragma unroll
      for (int j = 0; j < 2; ++j) {
        const int rloc = j * 8 + (lane >> 3);
        f32x4 v = *(const f32x4*)&tw[rloc * 36 + (lane & 7) * 4];
        vcs += v;
        __builtin_nontemporal_store(
            v, (f32x4*)(abase + (size_t)(qrow0 + rloc) * S_ + gc + (lane & 7) * 4));
      }
      float r0 = vcs[0], r1 = vcs[1], r2 = vcs[2], r3 = vcs[3];
      r0 += __shfl_xor(r0, 8); r0 += __shfl_xor(r0, 16); r0 += __shfl_xor(r0, 32);
      r1 += __shfl_xor(r1, 8); r1 += __shfl_xor(r1, 16); r1 += __shfl_xor(r1, 32);
      r2 += __shfl_xor(r2, 8); r2 += __shfl_xor(r2, 16); r2 += __shfl_xor(r2, 32);
      r3 += __shfl_xor(r3, 8); r3 += __shfl_xor(r3, 16); r3 += __shfl_xor(r3, 32);
      if (lane < 8) {
        f32x4 cw = {r0, r1, r2, r3};
        *(f32x4*)&colacc[wv >> 1][gc + lane * 4] = cw;
      }
    }
  }

  // ---------------- Column-sum flush: fixed-point u64 atomics -------------
  __syncthreads();
  unsigned long long* cb = c64 + (size_t)bh * 2048;
#pragma unroll
  for (int t = 0; t < 8; ++t) {
    const int k = t * 256 + tid;
    float cv = colacc[0][k] + colacc[1][k];
    unsigned int q = __float2uint_rn(cv * 16777216.0f);
    atomicAdd(&cb[k], (unsigned long long)q);
  }
}

// csum[b][h*64+d] = sum_k c[bh][k] * x[b][k][h*64+d]
__global__ __launch_bounds__(256) void csum_k(const unsigned long long* __restrict__ c64,
                                              const float* __restrict__ x,
                                              float* __restrict__ csum) {
  __shared__ float part[4][64];
  const int bh = blockIdx.x, b = bh >> 4, h = bh & 15;
  const int seg = threadIdx.x >> 6, d = threadIdx.x & 63;
  const unsigned long long* cb = c64 + (size_t)bh * 2048;
  const float* xb = x + (size_t)b * S_ * D_ + h * 64 + d;
  float acc = 0.f;
  for (int k = seg * 512; k < seg * 512 + 512; ++k) {
    float cv = (float)cb[k] * (1.0f / 16777216.0f);
    acc += cv * xb[(size_t)k * D_];
  }
  part[seg][d] = acc;
  __syncthreads();
  if (threadIdx.x < 64) {
    float s = part[0][d] + part[1][d] + part[2][d] + part[3][d];
    csum[b * D_ + h * 64 + d] = s;
  }
}

// out0[b][d] = sum_e csum[b][e] * W[d][e] + S * bias[d]
__global__ __launch_bounds__(256) void proj_k(const float* __restrict__ csum,
                                              const float* __restrict__ W,
                                              const float* __restrict__ bias,
                                              float* __restrict__ out0) {
  const int idx = blockIdx.x * 4 + (threadIdx.x >> 6); // (b,d) pair per wave
  const int b = idx >> 10, d = idx & 1023;
  const int lane = threadIdx.x & 63;
  const float* wr = W + (size_t)d * D_;
  const float* cs = csum + b * D_;
  float acc = 0.f;
#pragma unroll
  for (int e = 0; e < 16; ++e) acc += cs[lane + e * 64] * wr[lane + e * 64];
  acc += __shfl_xor(acc, 32);
  acc += __shfl_xor(acc, 16);
  acc += __shfl_xor(acc, 8);
  acc += __shfl_xor(acc, 4);
  acc += __shfl_xor(acc, 2);
  acc += __shfl_xor(acc, 1);
  if (lane == 0) out0[idx] = acc + 2048.0f * bias[d];
}

extern "C" void kernel_launch(void* const* d_in, const int* in_sizes, int n_in,
                              void* d_out, int out_size, void* d_ws, size_t ws_size,
                              hipStream_t stream) {
  const float* x    = (const float*)d_in[0];
  const int*   sl   = (const int*)d_in[1];
  const float* W    = (const float*)d_in[2];
  const float* bias = (const float*)d_in[3];

  float* out0 = (float*)d_out;
  float* attn = out0 + B_ * D_;

  unsigned long long* c64 = (unsigned long long*)d_ws;   // 64*2048*8 = 1 MB
  float* csum = (float*)(c64 + 64 * 2048);               // 4096 f32
  unsigned short* xh = (unsigned short*)(csum + 4096);   // bf16, 16 MB

  (void)hipMemsetAsync(c64, 0, (size_t)64 * 2048 * 8, stream);
  hipLaunchKernelGGL(xcvt,       dim3(2048), dim3(256), 0, stream, x, xh);
  hipLaunchKernelGGL(attn_fused, dim3(4096), dim3(256), 0, stream, xh, sl, attn, c64);
  hipLaunchKernelGGL(csum_k,     dim3(64),   dim3(256), 0, stream, c64, x, csum);
  hipLaunchKernelGGL(proj_k,     dim3(1024), dim3(256), 0, stream, csum, W, bias, out0);
}

// Round 6
// 389.149 us; speedup vs baseline: 2.0339x; 2.0339x over previous
//
#include <hip/hip_runtime.h>

// Problem constants
#define S_  2048
#define D_  1024
#define H_  16
#define B_  4

typedef __attribute__((ext_vector_type(8))) short short8;
typedef __attribute__((ext_vector_type(4))) float f32x4;

__device__ __forceinline__ unsigned short f2bf(float f) {
  unsigned int u = __float_as_uint(f);
  u += 0x7fffu + ((u >> 16) & 1u);      // round-to-nearest-even
  return (unsigned short)(u >> 16);
}
__device__ __forceinline__ unsigned int pack2(float a, float b) {
  return (unsigned int)f2bf(a) | ((unsigned int)f2bf(b) << 16);
}

// 0.125 (1/sqrt(DK)) * log2(e): use exp2 (native v_exp_f32)
#define SCL 0.18033688011112042f

// ---------------------------------------------------------------------------
// x (B,S,D) f32 -> xh (B,H,S,64) bf16 head-major (256 KB contiguous per bh).
// ---------------------------------------------------------------------------
__global__ __launch_bounds__(256) void xcvt(const float* __restrict__ x,
                                            unsigned short* __restrict__ xh) {
  const int n = blockIdx.x;
  const int bh = n >> 5, chunk = n & 31;
  const int b = bh >> 4, h = bh & 15;
  const int r = threadIdx.x >> 2, cg = threadIdx.x & 3;
  const int srow = chunk * 64 + r;
  const float* src = x + ((size_t)b * S_ + srow) * D_ + h * 64 + cg * 16;
  float4 v0 = ((const float4*)src)[0];
  float4 v1 = ((const float4*)src)[1];
  float4 v2 = ((const float4*)src)[2];
  float4 v3 = ((const float4*)src)[3];
  uint4 w0, w1;
  w0.x = pack2(v0.x, v0.y); w0.y = pack2(v0.z, v0.w);
  w0.z = pack2(v1.x, v1.y); w0.w = pack2(v1.z, v1.w);
  w1.x = pack2(v2.x, v2.y); w1.y = pack2(v2.z, v2.w);
  w1.z = pack2(v3.x, v3.y); w1.w = pack2(v3.z, v3.w);
  unsigned short* dst = xh + ((size_t)bh * S_ + srow) * 64 + cg * 16;
  *(uint4*)dst = w0;
  *(uint4*)(dst + 8) = w1;
}

// ---------------------------------------------------------------------------
// Two-pass fused attention (R1 structure, de-fattened).
// Block = 256 thr (4 waves x 16 q-rows) = 64-row q-tile, full S keys.
// K staged from pre-converted bf16 xh as pure uint4 copies into a
// double-buffered XOR-swizzled LDS tile; stage(c+1) issued before compute(c)
// so global loads hide under MFMA+exp. Pass A: row sums. Pass B: write attn
// + deterministic per-block column partials (cpart; no atomics).
// grid = 2048, XCD-swizzled (8 bh-slices per XCD -> K stays L2-resident).
// ---------------------------------------------------------------------------
__global__ __launch_bounds__(256, 4) void attn_fused(
    const unsigned short* __restrict__ xh, const int* __restrict__ sl32,
    float* __restrict__ attn, float* __restrict__ cpart)
{
  __shared__ __align__(16) unsigned short kbuf[2][128 * 64]; // 2 x 16 KB
  __shared__ float colbuf[2][4][128];                        // 4 KB

  const int n    = blockIdx.x;
  const int xcd  = n & 7;
  const int slot = n >> 3;                 // 0..255 per XCD
  const int bh   = (slot >> 5) * 8 + xcd;  // 8 bh-slices per XCD
  const int qt   = slot & 31;              // 32 q-tiles of 64 rows
  const int b    = bh >> 4;
  const int tid  = threadIdx.x;
  const int wv   = tid >> 6;
  const int lane = tid & 63;
  const int lo   = lane & 15;
  const int g    = lane >> 4;

  // seq_lens dtype auto-detect (values >= 1024 -> int64 layout has word1==0)
  const bool is64 = (sl32[1] == 0);
  const int seqlen = is64 ? sl32[2 * b] : sl32[b];

  const unsigned short* xk = xh + (size_t)bh * S_ * 64;
  const int qbase = qt * 64 + wv * 16;

  // Q fragment (A-frag): row = lo, k = g*8 + i (+32)
  short8 aq0 = *(const short8*)(xk + (size_t)(qbase + lo) * 64 + g * 8);
  short8 aq1 = *(const short8*)(xk + (size_t)(qbase + lo) * 64 + g * 8 + 32);

  // Staging: thread t -> key row k = t>>1, 64B half = t&1 (4 x uint4),
  // written XOR-swizzled: unit u -> u ^ (k&7).
  const int sk = tid >> 1, shf = tid & 1;
  auto stage = [&](unsigned short* dst, int c) {
    const uint4* src = (const uint4*)(xk + (size_t)(c * 128 + sk) * 64) + shf * 4;
    uint4* d = (uint4*)&dst[sk * 64];
    const int sw = sk & 7;
#pragma unroll
    for (int q = 0; q < 4; ++q) d[(shf * 4 + q) ^ sw] = src[q];
  };

  auto qk_tile = [&](const unsigned short* kb, int kt) -> f32x4 {
    const int key = kt * 16 + lo;
    const int cs = g ^ (key & 7);
    short8 b0 = *(const short8*)&kb[key * 64 + cs * 8];
    short8 b1 = *(const short8*)&kb[key * 64 + (cs ^ 4) * 8];
    f32x4 acc = {0.f, 0.f, 0.f, 0.f};
    acc = __builtin_amdgcn_mfma_f32_16x16x32_bf16(aq0, b0, acc, 0, 0, 0);
    acc = __builtin_amdgcn_mfma_f32_16x16x32_bf16(aq1, b1, acc, 0, 0, 0);
    return acc;
  };

  // ---------------- Pass A: row sums ----------------
  float rsum[4] = {0.f, 0.f, 0.f, 0.f};
  stage(kbuf[0], 0);
  __syncthreads();
  for (int c = 0; c < 16; ++c) {
    if (c < 15) stage(kbuf[(c + 1) & 1], c + 1);   // prefetch next chunk
    const unsigned short* kb = kbuf[c & 1];
#pragma unroll
    for (int kt = 0; kt < 8; ++kt) {
      f32x4 acc = qk_tile(kb, kt);
      const bool valid = (c * 128 + kt * 16 + lo) < seqlen;
#pragma unroll
      for (int r = 0; r < 4; ++r)
        rsum[r] += valid ? exp2f(acc[r] * SCL) : 0.f;
    }
    __syncthreads();
  }
#pragma unroll
  for (int r = 0; r < 4; ++r) {
    float v = rsum[r];
    v += __shfl_xor(v, 1);
    v += __shfl_xor(v, 2);
    v += __shfl_xor(v, 4);
    v += __shfl_xor(v, 8);
    rsum[r] = 1.0f / v;                 // 1/l for rows g*4+r
  }

  // ---------------- Pass B: write attn + column partials ----------------
  float* pr = attn + (size_t)bh * S_ * S_ + (size_t)(qbase + g * 4) * S_ + lo;
  float* cp = cpart + ((size_t)bh * 32 + qt) * 2048;
  stage(kbuf[0], 0);
  __syncthreads();
  for (int c = 0; c < 16; ++c) {
    if (c < 15) stage(kbuf[(c + 1) & 1], c + 1);
    const unsigned short* kb = kbuf[c & 1];
#pragma unroll
    for (int kt = 0; kt < 8; ++kt) {
      f32x4 acc = qk_tile(kb, kt);
      const bool valid = (c * 128 + kt * 16 + lo) < seqlen;
      float a0 = valid ? exp2f(acc[0] * SCL) * rsum[0] : 0.f;
      float a1 = valid ? exp2f(acc[1] * SCL) * rsum[1] : 0.f;
      float a2 = valid ? exp2f(acc[2] * SCL) * rsum[2] : 0.f;
      float a3 = valid ? exp2f(acc[3] * SCL) * rsum[3] : 0.f;
      const int off = c * 128 + kt * 16;
      __builtin_nontemporal_store(a0, pr + off);
      __builtin_nontemporal_store(a1, pr + (size_t)1 * S_ + off);
      __builtin_nontemporal_store(a2, pr + (size_t)2 * S_ + off);
      __builtin_nontemporal_store(a3, pr + (size_t)3 * S_ + off);
      float cv = a0 + a1 + a2 + a3;
      cv += __shfl_xor(cv, 16);
      cv += __shfl_xor(cv, 32);         // sum over the wave's 16 rows
      if (lane < 16) colbuf[c & 1][wv][kt * 16 + lo] = cv;
    }
    __syncthreads();
    // flush this chunk's column partials (other waves may already run c+1,
    // which writes colbuf[(c+1)&1] -- different buffer, no race)
    if (tid < 128)
      cp[c * 128 + tid] = colbuf[c & 1][0][tid] + colbuf[c & 1][1][tid] +
                          colbuf[c & 1][2][tid] + colbuf[c & 1][3][tid];
  }
}

// c[bh][k] = sum over 32 q-tiles of cpart
__global__ __launch_bounds__(256) void creduce(const float* __restrict__ cpart,
                                               float* __restrict__ c) {
  const int i = blockIdx.x * 256 + threadIdx.x;   // 64*2048 total
  const int bh = i >> 11, k = i & 2047;
  float s = 0.f;
#pragma unroll 8
  for (int qt = 0; qt < 32; ++qt) s += cpart[((size_t)bh * 32 + qt) * 2048 + k];
  c[i] = s;
}

// csum[b][h*64+d] = sum_k c[bh][k] * x[b][k][h*64+d]
__global__ __launch_bounds__(256) void csum_k(const float* __restrict__ c,
                                              const float* __restrict__ x,
                                              float* __restrict__ csum) {
  __shared__ float part[4][64];
  const int bh = blockIdx.x, b = bh >> 4, h = bh & 15;
  const int seg = threadIdx.x >> 6, d = threadIdx.x & 63;
  const float* cb = c + bh * 2048;
  const float* xb = x + (size_t)b * S_ * D_ + h * 64 + d;
  float acc = 0.f;
  for (int k = seg * 512; k < seg * 512 + 512; ++k)
    acc += cb[k] * xb[(size_t)k * D_];
  part[seg][d] = acc;
  __syncthreads();
  if (threadIdx.x < 64) {
    float s = part[0][d] + part[1][d] + part[2][d] + part[3][d];
    csum[b * D_ + h * 64 + d] = s;
  }
}

// out0[b][d] = sum_e csum[b][e] * W[d][e] + S * bias[d]
__global__ __launch_bounds__(256) void proj_k(const float* __restrict__ csum,
                                              const float* __restrict__ W,
                                              const float* __restrict__ bias,
                                              float* __restrict__ out0) {
  const int idx = blockIdx.x * 4 + (threadIdx.x >> 6); // (b,d) pair per wave
  const int b = idx >> 10, d = idx & 1023;
  const int lane = threadIdx.x & 63;
  const float* wr = W + (size_t)d * D_;
  const float* cs = csum + b * D_;
  float acc = 0.f;
#pragma unroll
  for (int e = 0; e < 16; ++e) acc += cs[lane + e * 64] * wr[lane + e * 64];
  acc += __shfl_xor(acc, 32);
  acc += __shfl_xor(acc, 16);
  acc += __shfl_xor(acc, 8);
  acc += __shfl_xor(acc, 4);
  acc += __shfl_xor(acc, 2);
  acc += __shfl_xor(acc, 1);
  if (lane == 0) out0[idx] = acc + 2048.0f * bias[d];
}

extern "C" void kernel_launch(void* const* d_in, const int* in_sizes, int n_in,
                              void* d_out, int out_size, void* d_ws, size_t ws_size,
                              hipStream_t stream) {
  const float* x    = (const float*)d_in[0];
  const int*   sl   = (const int*)d_in[1];
  const float* W    = (const float*)d_in[2];
  const float* bias = (const float*)d_in[3];

  float* out0 = (float*)d_out;
  float* attn = out0 + B_ * D_;

  float* cpart = (float*)d_ws;                       // 64*32*2048 f32 = 16 MB
  float* c     = cpart + (size_t)64 * 32 * 2048;     // 64*2048 f32 = 512 KB
  float* csum  = c + 64 * 2048;                      // 4096 f32
  unsigned short* xh = (unsigned short*)(csum + 4096); // bf16, 16 MB

  hipLaunchKernelGGL(xcvt,       dim3(2048), dim3(256), 0, stream, x, xh);
  hipLaunchKernelGGL(attn_fused, dim3(2048), dim3(256), 0, stream, xh, sl, attn, cpart);
  hipLaunchKernelGGL(creduce,    dim3(512),  dim3(256), 0, stream, cpart, c);
  hipLaunchKernelGGL(csum_k,     dim3(64),   dim3(256), 0, stream, c, x, csum);
  hipLaunchKernelGGL(proj_k,     dim3(1024), dim3(256), 0, stream, csum, W, bias, out0);
}